// Round 3
// baseline (2023.957 us; speedup 1.0000x reference)
//
#include <hip/hip_runtime.h>
#include <math.h>

#define NPTS 40000
#define KNBR 16
#define BN_EPS 1e-5f

// ---------------------------------------------------------------------------
// K1: per-point normals + B1[j][64] = [pos_j, normal_j] @ W1[0:6] + b1
// block = 256 threads = 4 points x 64 channels
// ---------------------------------------------------------------------------
__global__ __launch_bounds__(256, 4)
void k1_b1(const float* __restrict__ pos, const int* __restrict__ nbr,
           const float* __restrict__ W1, const float* __restrict__ b1,
           float* __restrict__ B1) {
    int p = blockIdx.x * 4 + (threadIdx.x >> 6);
    int k = threadIdx.x & 63;
    float px = pos[p * 3 + 0], py = pos[p * 3 + 1], pz = pos[p * 3 + 2];
    int n0 = nbr[p * KNBR + 0], n1 = nbr[p * KNBR + 1];
    float ax = pos[n0 * 3 + 0] - px, ay = pos[n0 * 3 + 1] - py, az = pos[n0 * 3 + 2] - pz;
    float bx = pos[n1 * 3 + 0] - px, by = pos[n1 * 3 + 1] - py, bz = pos[n1 * 3 + 2] - pz;
    float cx = ay * bz - az * by;
    float cy = az * bx - ax * bz;
    float cz = ax * by - ay * bx;
    float nrm = sqrtf(cx * cx + cy * cy + cz * cz);
    float inv = 1.0f / fmaxf(nrm, 1e-12f);
    float ux, uy, uz;
    if (nrm > 0.0f) { ux = cx * inv; uy = cy * inv; uz = cz * inv; }
    else            { ux = 0.0f;     uy = 0.0f;     uz = 1.0f;     }
    float acc = b1[k];
    acc = fmaf(px, W1[0 * 64 + k], acc);
    acc = fmaf(py, W1[1 * 64 + k], acc);
    acc = fmaf(pz, W1[2 * 64 + k], acc);
    acc = fmaf(ux, W1[3 * 64 + k], acc);
    acc = fmaf(uy, W1[4 * 64 + k], acc);
    acc = fmaf(uz, W1[5 * 64 + k], acc);
    B1[p * 64 + k] = acc;
}

// ---------------------------------------------------------------------------
// K2: conv1. h1[i][o] = relu( max_j( t_j . W2[:,o] ) + b2[o] )
//   t_j[k] = BN1(relu( B1[idx][k] + rel . W1[6:9,k] ))
// block = 128 threads (one per output channel o); W2 column in 64 VGPRs.
// ---------------------------------------------------------------------------
#define PTS2 8
__global__ __launch_bounds__(128, 2)
void k2_conv1(const float* __restrict__ pos, const int* __restrict__ nbr,
              const float* __restrict__ B1, const float* __restrict__ W1,
              const float* __restrict__ g1, const float* __restrict__ bt1,
              const float* __restrict__ m1, const float* __restrict__ v1,
              const float* __restrict__ W2, const float* __restrict__ b2,
              float* __restrict__ h1) {
    __shared__ float sh_t[64];
    const int o = threadIdx.x;
    float wcol[64];
#pragma unroll
    for (int k = 0; k < 64; ++k) wcol[k] = W2[k * 128 + o];
    const float b2o = b2[o];
    float w6 = 0.f, w7 = 0.f, w8 = 0.f, s1 = 0.f, o1 = 0.f;
    if (o < 64) {
        w6 = W1[6 * 64 + o]; w7 = W1[7 * 64 + o]; w8 = W1[8 * 64 + o];
        s1 = g1[o] * rsqrtf(v1[o] + BN_EPS);
        o1 = bt1[o] - m1[o] * s1;
    }
    const int base = blockIdx.x * PTS2;
    for (int p = 0; p < PTS2; ++p) {
        const int i = base + p;
        const float px = pos[i * 3 + 0], py = pos[i * 3 + 1], pz = pos[i * 3 + 2];
        float maxv = -INFINITY;
        for (int j = 0; j < 17; ++j) {
            const int idx = (j < 16) ? nbr[i * KNBR + j] : i;
            if (o < 64) {
                float rx = pos[idx * 3 + 0] - px;
                float ry = pos[idx * 3 + 1] - py;
                float rz = pos[idx * 3 + 2] - pz;
                float pre = B1[idx * 64 + o];
                pre = fmaf(rx, w6, pre);
                pre = fmaf(ry, w7, pre);
                pre = fmaf(rz, w8, pre);
                sh_t[o] = fmaf(fmaxf(pre, 0.f), s1, o1);
            }
            __syncthreads();
            float d0 = 0.f, d1 = 0.f, d2 = 0.f, d3 = 0.f;
            const float4* t4 = (const float4*)sh_t;
#pragma unroll
            for (int k4 = 0; k4 < 16; ++k4) {
                float4 t = t4[k4];
                d0 = fmaf(t.x, wcol[4 * k4 + 0], d0);
                d1 = fmaf(t.y, wcol[4 * k4 + 1], d1);
                d2 = fmaf(t.z, wcol[4 * k4 + 2], d2);
                d3 = fmaf(t.w, wcol[4 * k4 + 3], d3);
            }
            maxv = fmaxf(maxv, (d0 + d1) + (d2 + d3));
            __syncthreads();
        }
        h1[i * 128 + o] = fmaxf(maxv + b2o, 0.f);
    }
}

// ---------------------------------------------------------------------------
// K3: A2[i][o] = h1[i] . W3[0:128, o] + b3[o]   (no relu here)
// ---------------------------------------------------------------------------
#define PTS3 16
__global__ __launch_bounds__(128, 2)
void k3_a2(const float* __restrict__ h1, const float* __restrict__ W3,
           const float* __restrict__ b3, float* __restrict__ A2) {
    __shared__ float sh_h[128];
    const int o = threadIdx.x;
    float wcol[128];
#pragma unroll
    for (int k = 0; k < 128; ++k) wcol[k] = W3[k * 128 + o];
    const float b3o = b3[o];
    const int base = blockIdx.x * PTS3;
    for (int p = 0; p < PTS3; ++p) {
        const int i = base + p;
        sh_h[o] = h1[i * 128 + o];
        __syncthreads();
        float d0 = 0.f, d1 = 0.f, d2 = 0.f, d3 = 0.f;
        const float4* t4 = (const float4*)sh_h;
#pragma unroll
        for (int k4 = 0; k4 < 32; ++k4) {
            float4 t = t4[k4];
            d0 = fmaf(t.x, wcol[4 * k4 + 0], d0);
            d1 = fmaf(t.y, wcol[4 * k4 + 1], d1);
            d2 = fmaf(t.z, wcol[4 * k4 + 2], d2);
            d3 = fmaf(t.w, wcol[4 * k4 + 3], d3);
        }
        A2[i * 128 + o] = b3o + (d0 + d1) + (d2 + d3);
        __syncthreads();
    }
}

// ---------------------------------------------------------------------------
// K4: conv2 + classifier + log_softmax
//   t_j[k] = BN2(relu( A2[idx][k] + rel . W3[128:131, k] ))
//   h2[o]  = relu( max_j( t_j . W4[:, o] ) + b4[o] )
//   out[i] = log_softmax( h2 . Wc + bc )
// block = 256 threads (one per channel o of 256); W4 column in 128 VGPRs.
// ---------------------------------------------------------------------------
#define PTS4 16
__global__ __launch_bounds__(256, 2)
void k4_conv2(const float* __restrict__ pos, const int* __restrict__ nbr,
              const float* __restrict__ A2, const float* __restrict__ W3,
              const float* __restrict__ g2, const float* __restrict__ bt2,
              const float* __restrict__ m2, const float* __restrict__ v2,
              const float* __restrict__ W4, const float* __restrict__ b4,
              const float* __restrict__ Wc, const float* __restrict__ bc,
              float* __restrict__ out) {
    __shared__ float sh_t[128];
    __shared__ float sh_h2[256];
    const int o = threadIdx.x;
    float wcol[128];
#pragma unroll
    for (int k = 0; k < 128; ++k) wcol[k] = W4[k * 256 + o];
    const float b4o = b4[o];
    float w0 = 0.f, w1 = 0.f, w2 = 0.f, s2 = 0.f, o2 = 0.f;
    if (o < 128) {
        w0 = W3[128 * 128 + o];
        w1 = W3[129 * 128 + o];
        w2 = W3[130 * 128 + o];
        s2 = g2[o] * rsqrtf(v2[o] + BN_EPS);
        o2 = bt2[o] - m2[o] * s2;
    }
    const int base = blockIdx.x * PTS4;
    for (int p = 0; p < PTS4; ++p) {
        const int i = base + p;
        const float px = pos[i * 3 + 0], py = pos[i * 3 + 1], pz = pos[i * 3 + 2];
        float maxv = -INFINITY;
        for (int j = 0; j < 17; ++j) {
            const int idx = (j < 16) ? nbr[i * KNBR + j] : i;
            if (o < 128) {
                float rx = pos[idx * 3 + 0] - px;
                float ry = pos[idx * 3 + 1] - py;
                float rz = pos[idx * 3 + 2] - pz;
                float pre = A2[idx * 128 + o];
                pre = fmaf(rx, w0, pre);
                pre = fmaf(ry, w1, pre);
                pre = fmaf(rz, w2, pre);
                sh_t[o] = fmaf(fmaxf(pre, 0.f), s2, o2);
            }
            __syncthreads();
            float d0 = 0.f, d1 = 0.f, d2 = 0.f, d3 = 0.f;
            const float4* t4 = (const float4*)sh_t;
#pragma unroll
            for (int k4 = 0; k4 < 32; ++k4) {
                float4 t = t4[k4];
                d0 = fmaf(t.x, wcol[4 * k4 + 0], d0);
                d1 = fmaf(t.y, wcol[4 * k4 + 1], d1);
                d2 = fmaf(t.z, wcol[4 * k4 + 2], d2);
                d3 = fmaf(t.w, wcol[4 * k4 + 3], d3);
            }
            maxv = fmaxf(maxv, (d0 + d1) + (d2 + d3));
            __syncthreads();
        }
        sh_h2[o] = fmaxf(maxv + b4o, 0.f);
        __syncthreads();
        if (o < 64) {
            const int c = o & 7, kg = o >> 3;
            float part = 0.f;
#pragma unroll
            for (int k = 0; k < 32; ++k)
                part = fmaf(sh_h2[kg * 32 + k], Wc[(kg * 32 + k) * 8 + c], part);
            part += __shfl_xor(part, 8);
            part += __shfl_xor(part, 16);
            part += __shfl_xor(part, 32);
            float z = part + bc[c];
            float mz = z;
            mz = fmaxf(mz, __shfl_xor(mz, 1));
            mz = fmaxf(mz, __shfl_xor(mz, 2));
            mz = fmaxf(mz, __shfl_xor(mz, 4));
            float e = expf(z - mz);
            float se = e;
            se += __shfl_xor(se, 1);
            se += __shfl_xor(se, 2);
            se += __shfl_xor(se, 4);
            if (o < 8) out[i * 8 + o] = z - mz - logf(se);
        }
        __syncthreads();
    }
}

extern "C" void kernel_launch(void* const* d_in, const int* in_sizes, int n_in,
                              void* d_out, int out_size, void* d_ws, size_t ws_size,
                              hipStream_t stream) {
    const float* pos = (const float*)d_in[0];
    const int*   nbr = (const int*)d_in[1];
    const float* W1  = (const float*)d_in[2];
    const float* b1  = (const float*)d_in[3];
    const float* g1  = (const float*)d_in[4];
    const float* bt1 = (const float*)d_in[5];
    const float* m1  = (const float*)d_in[6];
    const float* v1  = (const float*)d_in[7];
    const float* W2  = (const float*)d_in[8];
    const float* b2  = (const float*)d_in[9];
    const float* W3  = (const float*)d_in[10];
    const float* b3  = (const float*)d_in[11];
    const float* g2  = (const float*)d_in[12];
    const float* bt2 = (const float*)d_in[13];
    const float* m2  = (const float*)d_in[14];
    const float* v2  = (const float*)d_in[15];
    const float* W4  = (const float*)d_in[16];
    const float* b4  = (const float*)d_in[17];
    const float* Wc  = (const float*)d_in[18];
    const float* bc  = (const float*)d_in[19];
    float* out = (float*)d_out;

    float* B1 = (float*)d_ws;                 // 40000*64  = 10.24 MB
    float* h1 = B1 + (size_t)NPTS * 64;       // 40000*128 = 20.48 MB
    float* A2 = h1 + (size_t)NPTS * 128;      // 40000*128 = 20.48 MB

    k1_b1<<<NPTS / 4, 256, 0, stream>>>(pos, nbr, W1, b1, B1);
    k2_conv1<<<NPTS / PTS2, 128, 0, stream>>>(pos, nbr, B1, W1, g1, bt1, m1, v1,
                                              W2, b2, h1);
    k3_a2<<<NPTS / PTS3, 128, 0, stream>>>(h1, W3, b3, A2);
    k4_conv2<<<NPTS / PTS4, 256, 0, stream>>>(pos, nbr, A2, W3, g2, bt2, m2, v2,
                                              W4, b4, Wc, bc, out);
}

// Round 4
// 1858.506 us; speedup vs baseline: 1.0890x; 1.0890x over previous
//
#include <hip/hip_runtime.h>
#include <math.h>

#define NPTS 40000
#define KNBR 16
#define BN_EPS 1e-5f

// ---------------------------------------------------------------------------
// K1: per-point normals + B1[j][64] = [pos_j, normal_j] @ W1[0:6] + b1
// ---------------------------------------------------------------------------
__global__ __launch_bounds__(256, 4)
void k1_b1(const float* __restrict__ pos, const int* __restrict__ nbr,
           const float* __restrict__ W1, const float* __restrict__ b1,
           float* __restrict__ B1) {
    int p = blockIdx.x * 4 + (threadIdx.x >> 6);
    int k = threadIdx.x & 63;
    float px = pos[p * 3 + 0], py = pos[p * 3 + 1], pz = pos[p * 3 + 2];
    int n0 = nbr[p * KNBR + 0], n1 = nbr[p * KNBR + 1];
    float ax = pos[n0 * 3 + 0] - px, ay = pos[n0 * 3 + 1] - py, az = pos[n0 * 3 + 2] - pz;
    float bx = pos[n1 * 3 + 0] - px, by = pos[n1 * 3 + 1] - py, bz = pos[n1 * 3 + 2] - pz;
    float cx = ay * bz - az * by;
    float cy = az * bx - ax * bz;
    float cz = ax * by - ay * bx;
    float nrm = sqrtf(cx * cx + cy * cy + cz * cz);
    float inv = 1.0f / fmaxf(nrm, 1e-12f);
    float ux, uy, uz;
    if (nrm > 0.0f) { ux = cx * inv; uy = cy * inv; uz = cz * inv; }
    else            { ux = 0.0f;     uy = 0.0f;     uz = 1.0f;     }
    float acc = b1[k];
    acc = fmaf(px, W1[0 * 64 + k], acc);
    acc = fmaf(py, W1[1 * 64 + k], acc);
    acc = fmaf(pz, W1[2 * 64 + k], acc);
    acc = fmaf(ux, W1[3 * 64 + k], acc);
    acc = fmaf(uy, W1[4 * 64 + k], acc);
    acc = fmaf(uz, W1[5 * 64 + k], acc);
    B1[p * 64 + k] = acc;
}

// ---------------------------------------------------------------------------
// K2: conv1, software-pipelined (double-buffered sh_t, 1 barrier / message).
//   t_j[k] = BN1(relu( B1[idx][k] + rel . W1[6:9,k] ))
//   h1[i][o] = relu( max_j( t_j . W2[:,o] ) + b2[o] )
// block = 128 threads; W2 column in 64 VGPRs.
// ---------------------------------------------------------------------------
#define PTS2 8
__global__ __launch_bounds__(128, 2)
void k2_conv1(const float* __restrict__ pos, const int* __restrict__ nbr,
              const float* __restrict__ B1, const float* __restrict__ W1,
              const float* __restrict__ g1, const float* __restrict__ bt1,
              const float* __restrict__ m1, const float* __restrict__ v1,
              const float* __restrict__ W2, const float* __restrict__ b2,
              float* __restrict__ h1) {
    __shared__ float sh_t[2][64];
    const int o = threadIdx.x;
    float wcol[64];
#pragma unroll
    for (int k = 0; k < 64; ++k) wcol[k] = W2[k * 128 + o];
    const float b2o = b2[o];
    float w6 = 0.f, w7 = 0.f, w8 = 0.f, s1 = 0.f, o1 = 0.f;
    if (o < 64) {
        w6 = W1[6 * 64 + o]; w7 = W1[7 * 64 + o]; w8 = W1[8 * 64 + o];
        s1 = g1[o] * rsqrtf(v1[o] + BN_EPS);
        o1 = bt1[o] - m1[o] * s1;
    }
    const int base = blockIdx.x * PTS2;
    for (int p = 0; p < PTS2; ++p) {
        const int i = base + p;
        const float px = pos[i * 3 + 0], py = pos[i * 3 + 1], pz = pos[i * 3 + 2];
        // prologue: message 0 -> sh_t[0]; prefetch message 1
        int idx0 = nbr[i * KNBR + 0];
        if (o < 64) {
            float pre = B1[idx0 * 64 + o];
            pre = fmaf(pos[idx0 * 3 + 0] - px, w6, pre);
            pre = fmaf(pos[idx0 * 3 + 1] - py, w7, pre);
            pre = fmaf(pos[idx0 * 3 + 2] - pz, w8, pre);
            sh_t[0][o] = fmaf(fmaxf(pre, 0.f), s1, o1);
        }
        float b1n = 0.f, nx = 0.f, ny = 0.f, nz = 0.f;
        int idx1 = nbr[i * KNBR + 1];
        if (o < 64) {
            b1n = B1[idx1 * 64 + o];
            nx = pos[idx1 * 3 + 0]; ny = pos[idx1 * 3 + 1]; nz = pos[idx1 * 3 + 2];
        }
        __syncthreads();
        float maxv = -INFINITY;
        for (int j = 0; j < 17; ++j) {
            if (j < 16 && o < 64) {               // write t_{j+1} (prefetched)
                float pre = b1n;
                pre = fmaf(nx - px, w6, pre);
                pre = fmaf(ny - py, w7, pre);
                pre = fmaf(nz - pz, w8, pre);
                sh_t[(j + 1) & 1][o] = fmaf(fmaxf(pre, 0.f), s1, o1);
            }
            if (j < 15) {                          // issue gather for j+2
                int idxn = (j + 2 < 16) ? nbr[i * KNBR + j + 2] : i;
                if (o < 64) {
                    b1n = B1[idxn * 64 + o];
                    nx = pos[idxn * 3 + 0]; ny = pos[idxn * 3 + 1]; nz = pos[idxn * 3 + 2];
                }
            }
            const float4* t4 = (const float4*)sh_t[j & 1];
            float d0 = 0.f, d1 = 0.f, d2 = 0.f, d3 = 0.f;
#pragma unroll
            for (int k4 = 0; k4 < 16; ++k4) {
                float4 t = t4[k4];
                d0 = fmaf(t.x, wcol[4 * k4 + 0], d0);
                d1 = fmaf(t.y, wcol[4 * k4 + 1], d1);
                d2 = fmaf(t.z, wcol[4 * k4 + 2], d2);
                d3 = fmaf(t.w, wcol[4 * k4 + 3], d3);
            }
            maxv = fmaxf(maxv, (d0 + d1) + (d2 + d3));
            __syncthreads();
        }
        h1[i * 128 + o] = fmaxf(maxv + b2o, 0.f);
    }
}

// ---------------------------------------------------------------------------
// K3: A2[i][o] = h1[i] . W3[0:128, o] + b3[o]  — row-prefetch pipeline
// ---------------------------------------------------------------------------
#define PTS3 16
__global__ __launch_bounds__(128, 2)
void k3_a2(const float* __restrict__ h1, const float* __restrict__ W3,
           const float* __restrict__ b3, float* __restrict__ A2) {
    __shared__ float sh_h[2][128];
    const int o = threadIdx.x;
    float wcol[128];
#pragma unroll
    for (int k = 0; k < 128; ++k) wcol[k] = W3[k * 128 + o];
    const float b3o = b3[o];
    const int base = blockIdx.x * PTS3;
    sh_h[0][o] = h1[(size_t)base * 128 + o];
    __syncthreads();
    for (int p = 0; p < PTS3; ++p) {
        float hn = 0.f;
        if (p < PTS3 - 1) hn = h1[(size_t)(base + p + 1) * 128 + o];
        const float4* t4 = (const float4*)sh_h[p & 1];
        float d0 = 0.f, d1 = 0.f, d2 = 0.f, d3 = 0.f;
#pragma unroll
        for (int k4 = 0; k4 < 32; ++k4) {
            float4 t = t4[k4];
            d0 = fmaf(t.x, wcol[4 * k4 + 0], d0);
            d1 = fmaf(t.y, wcol[4 * k4 + 1], d1);
            d2 = fmaf(t.z, wcol[4 * k4 + 2], d2);
            d3 = fmaf(t.w, wcol[4 * k4 + 3], d3);
        }
        A2[(size_t)(base + p) * 128 + o] = b3o + (d0 + d1) + (d2 + d3);
        if (p < PTS3 - 1) sh_h[(p + 1) & 1][o] = hn;
        __syncthreads();
    }
}

// ---------------------------------------------------------------------------
// K4: conv2 + classifier + log_softmax, software-pipelined (dbuf sh_t,
// 1 barrier / message). W4 column in 128 VGPRs.
// ---------------------------------------------------------------------------
#define PTS4 16
__global__ __launch_bounds__(256, 2)
void k4_conv2(const float* __restrict__ pos, const int* __restrict__ nbr,
              const float* __restrict__ A2, const float* __restrict__ W3,
              const float* __restrict__ g2, const float* __restrict__ bt2,
              const float* __restrict__ m2, const float* __restrict__ v2,
              const float* __restrict__ W4, const float* __restrict__ b4,
              const float* __restrict__ Wc, const float* __restrict__ bc,
              float* __restrict__ out) {
    __shared__ float sh_t[2][128];
    __shared__ float sh_h2[256];
    const int o = threadIdx.x;
    float wcol[128];
#pragma unroll
    for (int k = 0; k < 128; ++k) wcol[k] = W4[k * 256 + o];
    const float b4o = b4[o];
    float w0 = 0.f, w1 = 0.f, w2 = 0.f, s2 = 0.f, o2 = 0.f;
    if (o < 128) {
        w0 = W3[128 * 128 + o];
        w1 = W3[129 * 128 + o];
        w2 = W3[130 * 128 + o];
        s2 = g2[o] * rsqrtf(v2[o] + BN_EPS);
        o2 = bt2[o] - m2[o] * s2;
    }
    const int base = blockIdx.x * PTS4;
    for (int p = 0; p < PTS4; ++p) {
        const int i = base + p;
        const float px = pos[i * 3 + 0], py = pos[i * 3 + 1], pz = pos[i * 3 + 2];
        // prologue: message 0 -> sh_t[0]; prefetch message 1
        int idx0 = nbr[i * KNBR + 0];
        if (o < 128) {
            float pre = A2[(size_t)idx0 * 128 + o];
            pre = fmaf(pos[idx0 * 3 + 0] - px, w0, pre);
            pre = fmaf(pos[idx0 * 3 + 1] - py, w1, pre);
            pre = fmaf(pos[idx0 * 3 + 2] - pz, w2, pre);
            sh_t[0][o] = fmaf(fmaxf(pre, 0.f), s2, o2);
        }
        float a2n = 0.f, nx = 0.f, ny = 0.f, nz = 0.f;
        int idx1 = nbr[i * KNBR + 1];
        if (o < 128) {
            a2n = A2[(size_t)idx1 * 128 + o];
            nx = pos[idx1 * 3 + 0]; ny = pos[idx1 * 3 + 1]; nz = pos[idx1 * 3 + 2];
        }
        __syncthreads();
        float maxv = -INFINITY;
        for (int j = 0; j < 17; ++j) {
            if (j < 16 && o < 128) {              // write t_{j+1} (prefetched)
                float pre = a2n;
                pre = fmaf(nx - px, w0, pre);
                pre = fmaf(ny - py, w1, pre);
                pre = fmaf(nz - pz, w2, pre);
                sh_t[(j + 1) & 1][o] = fmaf(fmaxf(pre, 0.f), s2, o2);
            }
            if (j < 15) {                          // issue gather for j+2
                int idxn = (j + 2 < 16) ? nbr[i * KNBR + j + 2] : i;
                if (o < 128) {
                    a2n = A2[(size_t)idxn * 128 + o];
                    nx = pos[idxn * 3 + 0]; ny = pos[idxn * 3 + 1]; nz = pos[idxn * 3 + 2];
                }
            }
            const float4* t4 = (const float4*)sh_t[j & 1];
            float d0 = 0.f, d1 = 0.f, d2 = 0.f, d3 = 0.f;
#pragma unroll
            for (int k4 = 0; k4 < 32; ++k4) {
                float4 t = t4[k4];
                d0 = fmaf(t.x, wcol[4 * k4 + 0], d0);
                d1 = fmaf(t.y, wcol[4 * k4 + 1], d1);
                d2 = fmaf(t.z, wcol[4 * k4 + 2], d2);
                d3 = fmaf(t.w, wcol[4 * k4 + 3], d3);
            }
            maxv = fmaxf(maxv, (d0 + d1) + (d2 + d3));
            __syncthreads();
        }
        sh_h2[o] = fmaxf(maxv + b4o, 0.f);
        __syncthreads();
        if (o < 64) {
            const int c = o & 7, kg = o >> 3;
            float part = 0.f;
#pragma unroll
            for (int k = 0; k < 32; ++k)
                part = fmaf(sh_h2[kg * 32 + k], Wc[(kg * 32 + k) * 8 + c], part);
            part += __shfl_xor(part, 8);
            part += __shfl_xor(part, 16);
            part += __shfl_xor(part, 32);
            float z = part + bc[c];
            float mz = z;
            mz = fmaxf(mz, __shfl_xor(mz, 1));
            mz = fmaxf(mz, __shfl_xor(mz, 2));
            mz = fmaxf(mz, __shfl_xor(mz, 4));
            float e = expf(z - mz);
            float se = e;
            se += __shfl_xor(se, 1);
            se += __shfl_xor(se, 2);
            se += __shfl_xor(se, 4);
            if (o < 8) out[i * 8 + o] = z - mz - logf(se);
        }
        __syncthreads();
    }
}

extern "C" void kernel_launch(void* const* d_in, const int* in_sizes, int n_in,
                              void* d_out, int out_size, void* d_ws, size_t ws_size,
                              hipStream_t stream) {
    const float* pos = (const float*)d_in[0];
    const int*   nbr = (const int*)d_in[1];
    const float* W1  = (const float*)d_in[2];
    const float* b1  = (const float*)d_in[3];
    const float* g1  = (const float*)d_in[4];
    const float* bt1 = (const float*)d_in[5];
    const float* m1  = (const float*)d_in[6];
    const float* v1  = (const float*)d_in[7];
    const float* W2  = (const float*)d_in[8];
    const float* b2  = (const float*)d_in[9];
    const float* W3  = (const float*)d_in[10];
    const float* b3  = (const float*)d_in[11];
    const float* g2  = (const float*)d_in[12];
    const float* bt2 = (const float*)d_in[13];
    const float* m2  = (const float*)d_in[14];
    const float* v2  = (const float*)d_in[15];
    const float* W4  = (const float*)d_in[16];
    const float* b4  = (const float*)d_in[17];
    const float* Wc  = (const float*)d_in[18];
    const float* bc  = (const float*)d_in[19];
    float* out = (float*)d_out;

    float* B1 = (float*)d_ws;                 // 40000*64  = 10.24 MB
    float* h1 = B1 + (size_t)NPTS * 64;       // 40000*128 = 20.48 MB
    float* A2 = h1 + (size_t)NPTS * 128;      // 40000*128 = 20.48 MB

    k1_b1<<<NPTS / 4, 256, 0, stream>>>(pos, nbr, W1, b1, B1);
    k2_conv1<<<NPTS / PTS2, 128, 0, stream>>>(pos, nbr, B1, W1, g1, bt1, m1, v1,
                                              W2, b2, h1);
    k3_a2<<<NPTS / PTS3, 128, 0, stream>>>(h1, W3, b3, A2);
    k4_conv2<<<NPTS / PTS4, 256, 0, stream>>>(pos, nbr, A2, W3, g2, bt2, m2, v2,
                                              W4, b4, Wc, bc, out);
}

// Round 6
// 692.592 us; speedup vs baseline: 2.9223x; 2.6834x over previous
//
#include <hip/hip_runtime.h>
#include <math.h>

#define NPTS 40000
#define KNBR 16
#define BN_EPS 1e-5f

typedef __attribute__((ext_vector_type(8))) short v8s;
typedef __attribute__((ext_vector_type(4))) float f32x4;

__device__ __forceinline__ unsigned short f2bf(float f) {
    union { float f; unsigned int u; } c; c.f = f;
    unsigned int u = c.u + 0x7fffu + ((c.u >> 16) & 1u);   // RNE
    return (unsigned short)(u >> 16);
}

// ---------------------------------------------------------------------------
// K1: per-point normals + B1[j][64] = [pos_j, normal_j] @ W1[0:6] + b1
// ---------------------------------------------------------------------------
__global__ __launch_bounds__(256, 4)
void k1_b1(const float* __restrict__ pos, const int* __restrict__ nbr,
           const float* __restrict__ W1, const float* __restrict__ b1,
           float* __restrict__ B1) {
    int p = blockIdx.x * 4 + (threadIdx.x >> 6);
    int k = threadIdx.x & 63;
    float px = pos[p * 3 + 0], py = pos[p * 3 + 1], pz = pos[p * 3 + 2];
    int n0 = nbr[p * KNBR + 0], n1 = nbr[p * KNBR + 1];
    float ax = pos[n0 * 3 + 0] - px, ay = pos[n0 * 3 + 1] - py, az = pos[n0 * 3 + 2] - pz;
    float bx = pos[n1 * 3 + 0] - px, by = pos[n1 * 3 + 1] - py, bz = pos[n1 * 3 + 2] - pz;
    float cx = ay * bz - az * by;
    float cy = az * bx - ax * bz;
    float cz = ax * by - ay * bx;
    float nrm = sqrtf(cx * cx + cy * cy + cz * cz);
    float inv = 1.0f / fmaxf(nrm, 1e-12f);
    float ux, uy, uz;
    if (nrm > 0.0f) { ux = cx * inv; uy = cy * inv; uz = cz * inv; }
    else            { ux = 0.0f;     uy = 0.0f;     uz = 1.0f;     }
    float acc = b1[k];
    acc = fmaf(px, W1[0 * 64 + k], acc);
    acc = fmaf(py, W1[1 * 64 + k], acc);
    acc = fmaf(pz, W1[2 * 64 + k], acc);
    acc = fmaf(ux, W1[3 * 64 + k], acc);
    acc = fmaf(uy, W1[4 * 64 + k], acc);
    acc = fmaf(uz, W1[5 * 64 + k], acc);
    B1[p * 64 + k] = acc;
}

// ---------------------------------------------------------------------------
// K2: conv1 (unchanged this round; MFMA port next if k4 verifies)
// ---------------------------------------------------------------------------
#define PTS2 8
__global__ __launch_bounds__(128, 2)
void k2_conv1(const float* __restrict__ pos, const int* __restrict__ nbr,
              const float* __restrict__ B1, const float* __restrict__ W1,
              const float* __restrict__ g1, const float* __restrict__ bt1,
              const float* __restrict__ m1, const float* __restrict__ v1,
              const float* __restrict__ W2, const float* __restrict__ b2,
              float* __restrict__ h1) {
    __shared__ float sh_t[2][64];
    const int o = threadIdx.x;
    float wcol[64];
#pragma unroll
    for (int k = 0; k < 64; ++k) wcol[k] = W2[k * 128 + o];
    const float b2o = b2[o];
    float w6 = 0.f, w7 = 0.f, w8 = 0.f, s1 = 0.f, o1 = 0.f;
    if (o < 64) {
        w6 = W1[6 * 64 + o]; w7 = W1[7 * 64 + o]; w8 = W1[8 * 64 + o];
        s1 = g1[o] * rsqrtf(v1[o] + BN_EPS);
        o1 = bt1[o] - m1[o] * s1;
    }
    const int base = blockIdx.x * PTS2;
    for (int p = 0; p < PTS2; ++p) {
        const int i = base + p;
        const float px = pos[i * 3 + 0], py = pos[i * 3 + 1], pz = pos[i * 3 + 2];
        int idx0 = nbr[i * KNBR + 0];
        if (o < 64) {
            float pre = B1[idx0 * 64 + o];
            pre = fmaf(pos[idx0 * 3 + 0] - px, w6, pre);
            pre = fmaf(pos[idx0 * 3 + 1] - py, w7, pre);
            pre = fmaf(pos[idx0 * 3 + 2] - pz, w8, pre);
            sh_t[0][o] = fmaf(fmaxf(pre, 0.f), s1, o1);
        }
        float b1n = 0.f, nx = 0.f, ny = 0.f, nz = 0.f;
        int idx1 = nbr[i * KNBR + 1];
        if (o < 64) {
            b1n = B1[idx1 * 64 + o];
            nx = pos[idx1 * 3 + 0]; ny = pos[idx1 * 3 + 1]; nz = pos[idx1 * 3 + 2];
        }
        __syncthreads();
        float maxv = -INFINITY;
        for (int j = 0; j < 17; ++j) {
            if (j < 16 && o < 64) {
                float pre = b1n;
                pre = fmaf(nx - px, w6, pre);
                pre = fmaf(ny - py, w7, pre);
                pre = fmaf(nz - pz, w8, pre);
                sh_t[(j + 1) & 1][o] = fmaf(fmaxf(pre, 0.f), s1, o1);
            }
            if (j < 15) {
                int idxn = (j + 2 < 16) ? nbr[i * KNBR + j + 2] : i;
                if (o < 64) {
                    b1n = B1[idxn * 64 + o];
                    nx = pos[idxn * 3 + 0]; ny = pos[idxn * 3 + 1]; nz = pos[idxn * 3 + 2];
                }
            }
            const float4* t4 = (const float4*)sh_t[j & 1];
            float d0 = 0.f, d1 = 0.f, d2 = 0.f, d3 = 0.f;
#pragma unroll
            for (int k4 = 0; k4 < 16; ++k4) {
                float4 t = t4[k4];
                d0 = fmaf(t.x, wcol[4 * k4 + 0], d0);
                d1 = fmaf(t.y, wcol[4 * k4 + 1], d1);
                d2 = fmaf(t.z, wcol[4 * k4 + 2], d2);
                d3 = fmaf(t.w, wcol[4 * k4 + 3], d3);
            }
            maxv = fmaxf(maxv, (d0 + d1) + (d2 + d3));
            __syncthreads();
        }
        h1[i * 128 + o] = fmaxf(maxv + b2o, 0.f);
    }
}

// ---------------------------------------------------------------------------
// K3: A2[i][o] = h1[i] . W3[0:128, o] + b3[o]  (unchanged this round)
// ---------------------------------------------------------------------------
#define PTS3 16
__global__ __launch_bounds__(128, 2)
void k3_a2(const float* __restrict__ h1, const float* __restrict__ W3,
           const float* __restrict__ b3, float* __restrict__ A2) {
    __shared__ float sh_h[2][128];
    const int o = threadIdx.x;
    float wcol[128];
#pragma unroll
    for (int k = 0; k < 128; ++k) wcol[k] = W3[k * 128 + o];
    const float b3o = b3[o];
    const int base = blockIdx.x * PTS3;
    sh_h[0][o] = h1[(size_t)base * 128 + o];
    __syncthreads();
    for (int p = 0; p < PTS3; ++p) {
        float hn = 0.f;
        if (p < PTS3 - 1) hn = h1[(size_t)(base + p + 1) * 128 + o];
        const float4* t4 = (const float4*)sh_h[p & 1];
        float d0 = 0.f, d1 = 0.f, d2 = 0.f, d3 = 0.f;
#pragma unroll
        for (int k4 = 0; k4 < 32; ++k4) {
            float4 t = t4[k4];
            d0 = fmaf(t.x, wcol[4 * k4 + 0], d0);
            d1 = fmaf(t.y, wcol[4 * k4 + 1], d1);
            d2 = fmaf(t.z, wcol[4 * k4 + 2], d2);
            d3 = fmaf(t.w, wcol[4 * k4 + 3], d3);
        }
        A2[(size_t)(base + p) * 128 + o] = b3o + (d0 + d1) + (d2 + d3);
        if (p < PTS3 - 1) sh_h[(p + 1) & 1][o] = hn;
        __syncthreads();
    }
}

// ---------------------------------------------------------------------------
// K4 (MFMA): per point, S[32x256] = T[32x128] @ W4 via 16x16x32 bf16 MFMA.
// Block = 256 thr = 4 waves; wave w holds W4 cols [64w,64w+64) as B-frags in
// 64 VGPRs (loaded once). T built bf16 in XOR-swizzled LDS (T2 fix for the
// stride-256B A-frag reads). Rows 17..31 are padding (zeroed once).
// Epilogue: col-max over rows 0..16 + ReLU + classifier + log_softmax in regs.
// ---------------------------------------------------------------------------
#define PTS4 32
__global__ __launch_bounds__(256, 2)
void k4_conv2_mfma(const float* __restrict__ pos, const int* __restrict__ nbr,
                   const float* __restrict__ A2, const float* __restrict__ W3,
                   const float* __restrict__ g2, const float* __restrict__ bt2,
                   const float* __restrict__ m2, const float* __restrict__ v2,
                   const float* __restrict__ W4, const float* __restrict__ b4,
                   const float* __restrict__ Wc, const float* __restrict__ bc,
                   float* __restrict__ out) {
    __shared__ __align__(16) unsigned char Tl[32 * 256]; // 32 rows x 128ch bf16, swizzled
    __shared__ float sh_part[4][8];

    const int tid  = threadIdx.x;
    const int wv   = tid >> 6;          // wave id = msub
    const int lane = tid & 63;
    const int lgrp = lane >> 4;         // 0..3
    const int lmod = lane & 15;

    // ---- one-time: B fragments for W4 cols [wv*64, wv*64+64) ----
    v8s Bf[4][4];                        // [nt][kt]
#pragma unroll
    for (int nt = 0; nt < 4; ++nt) {
        const int col = wv * 64 + nt * 16 + lmod;
#pragma unroll
        for (int kt = 0; kt < 4; ++kt) {
#pragma unroll
            for (int j = 0; j < 8; ++j) {
                const int k = kt * 32 + lgrp * 8 + j;
                Bf[nt][kt][j] = (short)f2bf(W4[k * 256 + col]);
            }
        }
    }
    // ---- one-time: Wc rows + b4 for my 4 columns ----
    float wcls[4][8]; float b4c[4];
#pragma unroll
    for (int nt = 0; nt < 4; ++nt) {
        const int col = wv * 64 + nt * 16 + lmod;
        b4c[nt] = b4[col];
#pragma unroll
        for (int c = 0; c < 8; ++c) wcls[nt][c] = Wc[col * 8 + c];
    }
    // ---- one-time: build constants (2 channels per thread) ----
    const int ch0 = (tid & 63) * 2;
    const float bw0a = W3[128 * 128 + ch0],     bw1a = W3[129 * 128 + ch0],     bw2a = W3[130 * 128 + ch0];
    const float bw0b = W3[128 * 128 + ch0 + 1], bw1b = W3[129 * 128 + ch0 + 1], bw2b = W3[130 * 128 + ch0 + 1];
    const float sa = g2[ch0] * rsqrtf(v2[ch0] + BN_EPS);
    const float oa = bt2[ch0] - m2[ch0] * sa;
    const float sb = g2[ch0 + 1] * rsqrtf(v2[ch0 + 1] + BN_EPS);
    const float ob = bt2[ch0 + 1] - m2[ch0 + 1] * sb;

    // zero padding rows 17..31 (swizzle is row-internal, linear clear is fine)
    for (int z = tid; z < (32 - 17) * 64; z += 256)
        ((unsigned int*)(Tl + 17 * 256))[z] = 0u;

    const int base = blockIdx.x * PTS4;
    for (int p = 0; p < PTS4; ++p) {
        const int i = base + p;
        const float px = pos[i * 3 + 0], py = pos[i * 3 + 1], pz = pos[i * 3 + 2];

        // ---- build T rows 0..16 (msgs: 16 neighbors + self), bf16 swizzled ----
        float a2x[5], a2y[5], nx[5], ny[5], nz[5];
#pragma unroll
        for (int it = 0; it < 5; ++it) {
            const int m = it * 4 + wv;            // wave-uniform msg id
            if (m <= 16) {
                const int idx = (m < 16) ? nbr[i * KNBR + m] : i;
                const float2 a2 = *(const float2*)&A2[(size_t)idx * 128 + ch0];
                a2x[it] = a2.x; a2y[it] = a2.y;
                nx[it] = pos[idx * 3 + 0]; ny[it] = pos[idx * 3 + 1]; nz[it] = pos[idx * 3 + 2];
            }
        }
#pragma unroll
        for (int it = 0; it < 5; ++it) {
            const int m = it * 4 + wv;
            if (m <= 16) {
                const float rx = nx[it] - px, ry = ny[it] - py, rz = nz[it] - pz;
                float pa = a2x[it];
                pa = fmaf(rx, bw0a, pa); pa = fmaf(ry, bw1a, pa); pa = fmaf(rz, bw2a, pa);
                float pb = a2y[it];
                pb = fmaf(rx, bw0b, pb); pb = fmaf(ry, bw1b, pb); pb = fmaf(rz, bw2b, pb);
                const float ta = fmaf(fmaxf(pa, 0.f), sa, oa);
                const float tb = fmaf(fmaxf(pb, 0.f), sb, ob);
                const unsigned int w = (unsigned int)f2bf(ta) | ((unsigned int)f2bf(tb) << 16);
                int byte = m * 256 + ch0 * 2;
                byte ^= (m & 7) << 4;
                *(unsigned int*)(Tl + byte) = w;
            }
        }
        __syncthreads();                          // T ready

        // ---- GEMM: this wave computes S[0:32][wv*64 : wv*64+64) ----
        f32x4 acc0[4], acc1[4];
#pragma unroll
        for (int nt = 0; nt < 4; ++nt) {
            acc0[nt] = f32x4{0.f, 0.f, 0.f, 0.f};
            acc1[nt] = f32x4{0.f, 0.f, 0.f, 0.f};
        }
#pragma unroll
        for (int kt = 0; kt < 4; ++kt) {
            int b0 = lmod * 256 + kt * 64 + lgrp * 16;          // row = lmod
            b0 ^= (lmod & 7) << 4;
            int b1 = (16 + lmod) * 256 + kt * 64 + lgrp * 16;   // row = 16+lmod
            b1 ^= (lmod & 7) << 4;
            const v8s a0 = *(const v8s*)(Tl + b0);
            const v8s a1 = *(const v8s*)(Tl + b1);
#pragma unroll
            for (int nt = 0; nt < 4; ++nt) {
                acc0[nt] = __builtin_amdgcn_mfma_f32_16x16x32_bf16(a0, Bf[nt][kt], acc0[nt], 0, 0, 0);
                acc1[nt] = __builtin_amdgcn_mfma_f32_16x16x32_bf16(a1, Bf[nt][kt], acc1[nt], 0, 0, 0);
            }
        }

        // ---- max over rows 0..16, +b4, ReLU, classifier partials ----
        float part[8];
#pragma unroll
        for (int c = 0; c < 8; ++c) part[c] = 0.f;
#pragma unroll
        for (int nt = 0; nt < 4; ++nt) {
            float mv = fmaxf(fmaxf(acc0[nt][0], acc0[nt][1]),
                             fmaxf(acc0[nt][2], acc0[nt][3]));   // rows lgrp*4+0..3
            mv = fmaxf(mv, __shfl_xor(mv, 16));
            mv = fmaxf(mv, __shfl_xor(mv, 32));                  // rows 0..15, col lmod
            const float s16 = __shfl(acc1[nt][0], lmod);         // row 16 (from lanes 0..15)
            const float h = fmaxf(fmaxf(mv, s16) + b4c[nt], 0.f);
#pragma unroll
            for (int c = 0; c < 8; ++c) part[c] = fmaf(h, wcls[nt][c], part[c]);
        }
#pragma unroll
        for (int c = 0; c < 8; ++c) {                            // sum 16 distinct cols
            part[c] += __shfl_xor(part[c], 1);
            part[c] += __shfl_xor(part[c], 2);
            part[c] += __shfl_xor(part[c], 4);
            part[c] += __shfl_xor(part[c], 8);
        }
        if (lane == 0) {
#pragma unroll
            for (int c = 0; c < 8; ++c) sh_part[wv][c] = part[c];
        }
        __syncthreads();                          // sh_part ready; all T reads done
        if (tid < 8) {
            const float z = sh_part[0][tid] + sh_part[1][tid] +
                            sh_part[2][tid] + sh_part[3][tid] + bc[tid];
            float mz = z;
            mz = fmaxf(mz, __shfl_xor(mz, 1));
            mz = fmaxf(mz, __shfl_xor(mz, 2));
            mz = fmaxf(mz, __shfl_xor(mz, 4));
            const float e = expf(z - mz);
            float se = e;
            se += __shfl_xor(se, 1);
            se += __shfl_xor(se, 2);
            se += __shfl_xor(se, 4);
            out[(size_t)i * 8 + tid] = z - mz - logf(se);
        }
    }
}

extern "C" void kernel_launch(void* const* d_in, const int* in_sizes, int n_in,
                              void* d_out, int out_size, void* d_ws, size_t ws_size,
                              hipStream_t stream) {
    const float* pos = (const float*)d_in[0];
    const int*   nbr = (const int*)d_in[1];
    const float* W1  = (const float*)d_in[2];
    const float* b1  = (const float*)d_in[3];
    const float* g1  = (const float*)d_in[4];
    const float* bt1 = (const float*)d_in[5];
    const float* m1  = (const float*)d_in[6];
    const float* v1  = (const float*)d_in[7];
    const float* W2  = (const float*)d_in[8];
    const float* b2  = (const float*)d_in[9];
    const float* W3  = (const float*)d_in[10];
    const float* b3  = (const float*)d_in[11];
    const float* g2  = (const float*)d_in[12];
    const float* bt2 = (const float*)d_in[13];
    const float* m2  = (const float*)d_in[14];
    const float* v2  = (const float*)d_in[15];
    const float* W4  = (const float*)d_in[16];
    const float* b4  = (const float*)d_in[17];
    const float* Wc  = (const float*)d_in[18];
    const float* bc  = (const float*)d_in[19];
    float* out = (float*)d_out;

    float* B1 = (float*)d_ws;                 // 40000*64  = 10.24 MB
    float* h1 = B1 + (size_t)NPTS * 64;       // 40000*128 = 20.48 MB
    float* A2 = h1 + (size_t)NPTS * 128;      // 40000*128 = 20.48 MB

    k1_b1<<<NPTS / 4, 256, 0, stream>>>(pos, nbr, W1, b1, B1);
    k2_conv1<<<NPTS / PTS2, 128, 0, stream>>>(pos, nbr, B1, W1, g1, bt1, m1, v1,
                                              W2, b2, h1);
    k3_a2<<<NPTS / PTS3, 128, 0, stream>>>(h1, W3, b3, A2);
    k4_conv2_mfma<<<NPTS / PTS4, 256, 0, stream>>>(pos, nbr, A2, W3, g2, bt2, m2, v2,
                                                   W4, b4, Wc, bc, out);
}

// Round 7
// 557.258 us; speedup vs baseline: 3.6320x; 1.2429x over previous
//
#include <hip/hip_runtime.h>
#include <math.h>

#define NPTS 40000
#define KNBR 16
#define BN_EPS 1e-5f

typedef __attribute__((ext_vector_type(8))) short v8s;
typedef __attribute__((ext_vector_type(4))) float f32x4;

__device__ __forceinline__ unsigned short f2bf(float f) {
    union { float f; unsigned int u; } c; c.f = f;
    unsigned int u = c.u + 0x7fffu + ((c.u >> 16) & 1u);   // RNE
    return (unsigned short)(u >> 16);
}

// ---------------------------------------------------------------------------
// K1: per-point normals + B1[j][64] = [pos_j, normal_j] @ W1[0:6] + b1
// ---------------------------------------------------------------------------
__global__ __launch_bounds__(256, 4)
void k1_b1(const float* __restrict__ pos, const int* __restrict__ nbr,
           const float* __restrict__ W1, const float* __restrict__ b1,
           float* __restrict__ B1) {
    int p = blockIdx.x * 4 + (threadIdx.x >> 6);
    int k = threadIdx.x & 63;
    float px = pos[p * 3 + 0], py = pos[p * 3 + 1], pz = pos[p * 3 + 2];
    int n0 = nbr[p * KNBR + 0], n1 = nbr[p * KNBR + 1];
    float ax = pos[n0 * 3 + 0] - px, ay = pos[n0 * 3 + 1] - py, az = pos[n0 * 3 + 2] - pz;
    float bx = pos[n1 * 3 + 0] - px, by = pos[n1 * 3 + 1] - py, bz = pos[n1 * 3 + 2] - pz;
    float cx = ay * bz - az * by;
    float cy = az * bx - ax * bz;
    float cz = ax * by - ay * bx;
    float nrm = sqrtf(cx * cx + cy * cy + cz * cz);
    float inv = 1.0f / fmaxf(nrm, 1e-12f);
    float ux, uy, uz;
    if (nrm > 0.0f) { ux = cx * inv; uy = cy * inv; uz = cz * inv; }
    else            { ux = 0.0f;     uy = 0.0f;     uz = 1.0f;     }
    float acc = b1[k];
    acc = fmaf(px, W1[0 * 64 + k], acc);
    acc = fmaf(py, W1[1 * 64 + k], acc);
    acc = fmaf(pz, W1[2 * 64 + k], acc);
    acc = fmaf(ux, W1[3 * 64 + k], acc);
    acc = fmaf(uy, W1[4 * 64 + k], acc);
    acc = fmaf(uz, W1[5 * 64 + k], acc);
    B1[p * 64 + k] = acc;
}

// ---------------------------------------------------------------------------
// K2 (MFMA, k3 folded): per point, S[32x128] = T1[32x64] @ W2; h1 -> LDS H
// tile (bf16); at block end A2[32x128] = H @ W3[0:128] + b3 (one GEMM, no
// padding waste). Dbuf T1, 1 barrier/point, gather prefetch.
// ---------------------------------------------------------------------------
#define PTS2 32
__global__ __launch_bounds__(256, 2)
void k2_conv1_mfma(const float* __restrict__ pos, const int* __restrict__ nbr,
                   const float* __restrict__ B1, const float* __restrict__ W1,
                   const float* __restrict__ g1, const float* __restrict__ bt1,
                   const float* __restrict__ m1, const float* __restrict__ v1,
                   const float* __restrict__ W2, const float* __restrict__ b2,
                   const float* __restrict__ W3, const float* __restrict__ b3,
                   float* __restrict__ A2) {
    __shared__ __align__(16) unsigned char Tl[2][32 * 128]; // 32 rows x 64ch bf16, swizzled
    __shared__ __align__(16) unsigned char Hl[32 * 256];    // 32 pts x 128ch bf16, swizzled

    const int tid  = threadIdx.x;
    const int wv   = tid >> 6;
    const int lane = tid & 63;
    const int lgrp = lane >> 4;
    const int lmod = lane & 15;

    // B-frags for W2 cols [wv*32, wv*32+32): nt 0/1, kt 0/1 (K=64)
    v8s Bf2[2][2];
    float b2c[2];
#pragma unroll
    for (int nt = 0; nt < 2; ++nt) {
        const int col = wv * 32 + nt * 16 + lmod;
        b2c[nt] = b2[col];
#pragma unroll
        for (int kt = 0; kt < 2; ++kt)
#pragma unroll
            for (int j = 0; j < 8; ++j)
                Bf2[nt][kt][j] = (short)f2bf(W2[(kt * 32 + lgrp * 8 + j) * 128 + col]);
    }
    // T-build constants: 2 channels of 64 per thread
    const int ch0 = (lane & 31) * 2;
    const int rsub = lane >> 5;
    const float w6a = W1[6 * 64 + ch0],     w7a = W1[7 * 64 + ch0],     w8a = W1[8 * 64 + ch0];
    const float w6b = W1[6 * 64 + ch0 + 1], w7b = W1[7 * 64 + ch0 + 1], w8b = W1[8 * 64 + ch0 + 1];
    const float s1a = g1[ch0] * rsqrtf(v1[ch0] + BN_EPS);
    const float o1a = bt1[ch0] - m1[ch0] * s1a;
    const float s1b = g1[ch0 + 1] * rsqrtf(v1[ch0 + 1] + BN_EPS);
    const float o1b = bt1[ch0 + 1] - m1[ch0 + 1] * s1b;

    // zero pad rows 17..31 of both T buffers (swizzle is row-internal)
    for (int z = tid; z < 2 * 15 * 32; z += 256) {
        const int b = z / (15 * 32), r = z % (15 * 32);
        ((unsigned int*)(Tl[b] + 17 * 128))[r] = 0u;
    }

    const int base = blockIdx.x * PTS2;
    // ---- prologue: build T for p=0 ----
    {
        const int i = base;
        const float cx = pos[i * 3 + 0], cy = pos[i * 3 + 1], cz = pos[i * 3 + 2];
#pragma unroll
        for (int it = 0; it < 3; ++it) {
            const int m = it * 8 + wv * 2 + rsub;
            if (m <= 16) {
                const int idx = (m < 16) ? nbr[i * KNBR + m] : i;
                const float2 a = *(const float2*)&B1[(size_t)idx * 64 + ch0];
                const float rx = pos[idx * 3 + 0] - cx;
                const float ry = pos[idx * 3 + 1] - cy;
                const float rz = pos[idx * 3 + 2] - cz;
                float pa = a.x;
                pa = fmaf(rx, w6a, pa); pa = fmaf(ry, w7a, pa); pa = fmaf(rz, w8a, pa);
                float pb = a.y;
                pb = fmaf(rx, w6b, pb); pb = fmaf(ry, w7b, pb); pb = fmaf(rz, w8b, pb);
                const float ta = fmaf(fmaxf(pa, 0.f), s1a, o1a);
                const float tb = fmaf(fmaxf(pb, 0.f), s1b, o1b);
                const unsigned int w = (unsigned int)f2bf(ta) | ((unsigned int)f2bf(tb) << 16);
                int byte = m * 128 + ch0 * 2;
                byte ^= (m & 7) << 4;
                *(unsigned int*)(Tl[0] + byte) = w;
            }
        }
    }
    __syncthreads();

    float aNx[3], aNy[3], qNx[3], qNy[3], qNz[3];
    float cNx = 0.f, cNy = 0.f, cNz = 0.f;
    for (int p = 0; p < PTS2; ++p) {
        const int buf = p & 1;
        // ---- prefetch gathers for p+1 ----
        if (p < PTS2 - 1) {
            const int in_ = base + p + 1;
            cNx = pos[in_ * 3 + 0]; cNy = pos[in_ * 3 + 1]; cNz = pos[in_ * 3 + 2];
#pragma unroll
            for (int it = 0; it < 3; ++it) {
                const int m = it * 8 + wv * 2 + rsub;
                if (m <= 16) {
                    const int idx = (m < 16) ? nbr[in_ * KNBR + m] : in_;
                    const float2 a = *(const float2*)&B1[(size_t)idx * 64 + ch0];
                    aNx[it] = a.x; aNy[it] = a.y;
                    qNx[it] = pos[idx * 3 + 0]; qNy[it] = pos[idx * 3 + 1]; qNz[it] = pos[idx * 3 + 2];
                }
            }
        }
        // ---- GEMM on buf ----
        f32x4 acc0[2], acc1[2];
#pragma unroll
        for (int nt = 0; nt < 2; ++nt) {
            acc0[nt] = f32x4{0.f, 0.f, 0.f, 0.f};
            acc1[nt] = f32x4{0.f, 0.f, 0.f, 0.f};
        }
#pragma unroll
        for (int kt = 0; kt < 2; ++kt) {
            int b0 = lmod * 128 + kt * 64 + lgrp * 16;
            b0 ^= (lmod & 7) << 4;
            const int b1r = b0 + 16 * 128;
            const v8s a0 = *(const v8s*)(Tl[buf] + b0);
            const v8s a1 = *(const v8s*)(Tl[buf] + b1r);
#pragma unroll
            for (int nt = 0; nt < 2; ++nt) {
                acc0[nt] = __builtin_amdgcn_mfma_f32_16x16x32_bf16(a0, Bf2[nt][kt], acc0[nt], 0, 0, 0);
                acc1[nt] = __builtin_amdgcn_mfma_f32_16x16x32_bf16(a1, Bf2[nt][kt], acc1[nt], 0, 0, 0);
            }
        }
        // ---- epilogue: max over rows 0..16, ReLU, h -> H tile (bf16) ----
#pragma unroll
        for (int nt = 0; nt < 2; ++nt) {
            float mv = fmaxf(fmaxf(acc0[nt][0], acc0[nt][1]),
                             fmaxf(acc0[nt][2], acc0[nt][3]));
            mv = fmaxf(mv, __shfl_xor(mv, 16));
            mv = fmaxf(mv, __shfl_xor(mv, 32));
            const float s16 = __shfl(acc1[nt][0], lmod);
            const float h = fmaxf(fmaxf(mv, s16) + b2c[nt], 0.f);
            if (lgrp == 0) {
                int hb = p * 256 + (wv * 32 + nt * 16 + lmod) * 2;
                hb ^= (p & 7) << 4;
                *(unsigned short*)(Hl + hb) = f2bf(h);
            }
        }
        // ---- build T for p+1 into buf^1 ----
        if (p < PTS2 - 1) {
#pragma unroll
            for (int it = 0; it < 3; ++it) {
                const int m = it * 8 + wv * 2 + rsub;
                if (m <= 16) {
                    const float rx = qNx[it] - cNx, ry = qNy[it] - cNy, rz = qNz[it] - cNz;
                    float pa = aNx[it];
                    pa = fmaf(rx, w6a, pa); pa = fmaf(ry, w7a, pa); pa = fmaf(rz, w8a, pa);
                    float pb = aNy[it];
                    pb = fmaf(rx, w6b, pb); pb = fmaf(ry, w7b, pb); pb = fmaf(rz, w8b, pb);
                    const float ta = fmaf(fmaxf(pa, 0.f), s1a, o1a);
                    const float tb = fmaf(fmaxf(pb, 0.f), s1b, o1b);
                    const unsigned int w = (unsigned int)f2bf(ta) | ((unsigned int)f2bf(tb) << 16);
                    int byte = m * 128 + ch0 * 2;
                    byte ^= (m & 7) << 4;
                    *(unsigned int*)(Tl[buf ^ 1] + byte) = w;
                }
            }
        }
        __syncthreads();
    }

    // ---- block epilogue: A2[32x128] = H @ W3[0:128] + b3 ----
    v8s Wf3[2][4];
    float b3c[2];
#pragma unroll
    for (int nt = 0; nt < 2; ++nt) {
        const int col = wv * 32 + nt * 16 + lmod;
        b3c[nt] = b3[col];
#pragma unroll
        for (int kt = 0; kt < 4; ++kt)
#pragma unroll
            for (int j = 0; j < 8; ++j)
                Wf3[nt][kt][j] = (short)f2bf(W3[(kt * 32 + lgrp * 8 + j) * 128 + col]);
    }
    f32x4 accA[2][2];
#pragma unroll
    for (int mt = 0; mt < 2; ++mt)
#pragma unroll
        for (int nt = 0; nt < 2; ++nt) accA[mt][nt] = f32x4{0.f, 0.f, 0.f, 0.f};
#pragma unroll
    for (int kt = 0; kt < 4; ++kt) {
#pragma unroll
        for (int mt = 0; mt < 2; ++mt) {
            int ba = (mt * 16 + lmod) * 256 + kt * 64 + lgrp * 16;
            ba ^= (lmod & 7) << 4;
            const v8s aH = *(const v8s*)(Hl + ba);
#pragma unroll
            for (int nt = 0; nt < 2; ++nt)
                accA[mt][nt] = __builtin_amdgcn_mfma_f32_16x16x32_bf16(aH, Wf3[nt][kt], accA[mt][nt], 0, 0, 0);
        }
    }
#pragma unroll
    for (int mt = 0; mt < 2; ++mt)
#pragma unroll
        for (int nt = 0; nt < 2; ++nt)
#pragma unroll
            for (int reg = 0; reg < 4; ++reg) {
                const int row = base + mt * 16 + lgrp * 4 + reg;
                const int col = wv * 32 + nt * 16 + lmod;
                A2[(size_t)row * 128 + col] = accA[mt][nt][reg] + b3c[nt];
            }
}

// ---------------------------------------------------------------------------
// K4 (MFMA, pipelined): dbuf T, 1 barrier/point, gather prefetch.
// S[32x256] = T[32x128] @ W4; wave holds 64 W4 cols as B-frags.
// Epilogue: col-max rows 0..16 + ReLU + classifier + log_softmax.
// ---------------------------------------------------------------------------
#define PTS4 32
__global__ __launch_bounds__(256, 2)
void k4_conv2_mfma(const float* __restrict__ pos, const int* __restrict__ nbr,
                   const float* __restrict__ A2, const float* __restrict__ W3,
                   const float* __restrict__ g2, const float* __restrict__ bt2,
                   const float* __restrict__ m2, const float* __restrict__ v2,
                   const float* __restrict__ W4, const float* __restrict__ b4,
                   const float* __restrict__ Wc, const float* __restrict__ bc,
                   float* __restrict__ out) {
    __shared__ __align__(16) unsigned char Tl[2][32 * 256];
    __shared__ float sh_part[2][4][8];

    const int tid  = threadIdx.x;
    const int wv   = tid >> 6;
    const int lane = tid & 63;
    const int lgrp = lane >> 4;
    const int lmod = lane & 15;

    v8s Bf[4][4];
#pragma unroll
    for (int nt = 0; nt < 4; ++nt) {
        const int col = wv * 64 + nt * 16 + lmod;
#pragma unroll
        for (int kt = 0; kt < 4; ++kt)
#pragma unroll
            for (int j = 0; j < 8; ++j)
                Bf[nt][kt][j] = (short)f2bf(W4[(kt * 32 + lgrp * 8 + j) * 256 + col]);
    }
    float wcls[4][8]; float b4c[4];
#pragma unroll
    for (int nt = 0; nt < 4; ++nt) {
        const int col = wv * 64 + nt * 16 + lmod;
        b4c[nt] = b4[col];
#pragma unroll
        for (int c = 0; c < 8; ++c) wcls[nt][c] = Wc[col * 8 + c];
    }
    const int ch0 = lane * 2;
    const float bw0a = W3[128 * 128 + ch0],     bw1a = W3[129 * 128 + ch0],     bw2a = W3[130 * 128 + ch0];
    const float bw0b = W3[128 * 128 + ch0 + 1], bw1b = W3[129 * 128 + ch0 + 1], bw2b = W3[130 * 128 + ch0 + 1];
    const float sa = g2[ch0] * rsqrtf(v2[ch0] + BN_EPS);
    const float oa = bt2[ch0] - m2[ch0] * sa;
    const float sb = g2[ch0 + 1] * rsqrtf(v2[ch0 + 1] + BN_EPS);
    const float ob = bt2[ch0 + 1] - m2[ch0 + 1] * sb;

    for (int z = tid; z < 2 * 15 * 64; z += 256) {
        const int b = z / (15 * 64), r = z % (15 * 64);
        ((unsigned int*)(Tl[b] + 17 * 256))[r] = 0u;
    }

    const int base = blockIdx.x * PTS4;
    // ---- prologue: build T for p=0 ----
    {
        const int i = base;
        const float cx = pos[i * 3 + 0], cy = pos[i * 3 + 1], cz = pos[i * 3 + 2];
#pragma unroll
        for (int it = 0; it < 5; ++it) {
            const int m = it * 4 + wv;
            if (m <= 16) {
                const int idx = (m < 16) ? nbr[i * KNBR + m] : i;
                const float2 a = *(const float2*)&A2[(size_t)idx * 128 + ch0];
                const float rx = pos[idx * 3 + 0] - cx;
                const float ry = pos[idx * 3 + 1] - cy;
                const float rz = pos[idx * 3 + 2] - cz;
                float pa = a.x;
                pa = fmaf(rx, bw0a, pa); pa = fmaf(ry, bw1a, pa); pa = fmaf(rz, bw2a, pa);
                float pb = a.y;
                pb = fmaf(rx, bw0b, pb); pb = fmaf(ry, bw1b, pb); pb = fmaf(rz, bw2b, pb);
                const float ta = fmaf(fmaxf(pa, 0.f), sa, oa);
                const float tb = fmaf(fmaxf(pb, 0.f), sb, ob);
                const unsigned int w = (unsigned int)f2bf(ta) | ((unsigned int)f2bf(tb) << 16);
                int byte = m * 256 + ch0 * 2;
                byte ^= (m & 7) << 4;
                *(unsigned int*)(Tl[0] + byte) = w;
            }
        }
    }
    __syncthreads();

    float aNx[5], aNy[5], qNx[5], qNy[5], qNz[5];
    float cNx = 0.f, cNy = 0.f, cNz = 0.f;
    for (int p = 0; p < PTS4; ++p) {
        const int buf = p & 1;
        // ---- prefetch gathers for p+1 ----
        if (p < PTS4 - 1) {
            const int in_ = base + p + 1;
            cNx = pos[in_ * 3 + 0]; cNy = pos[in_ * 3 + 1]; cNz = pos[in_ * 3 + 2];
#pragma unroll
            for (int it = 0; it < 5; ++it) {
                const int m = it * 4 + wv;
                if (m <= 16) {
                    const int idx = (m < 16) ? nbr[in_ * KNBR + m] : in_;
                    const float2 a = *(const float2*)&A2[(size_t)idx * 128 + ch0];
                    aNx[it] = a.x; aNy[it] = a.y;
                    qNx[it] = pos[idx * 3 + 0]; qNy[it] = pos[idx * 3 + 1]; qNz[it] = pos[idx * 3 + 2];
                }
            }
        }
        // ---- GEMM on buf ----
        f32x4 acc0[4], acc1[4];
#pragma unroll
        for (int nt = 0; nt < 4; ++nt) {
            acc0[nt] = f32x4{0.f, 0.f, 0.f, 0.f};
            acc1[nt] = f32x4{0.f, 0.f, 0.f, 0.f};
        }
#pragma unroll
        for (int kt = 0; kt < 4; ++kt) {
            int b0 = lmod * 256 + kt * 64 + lgrp * 16;
            b0 ^= (lmod & 7) << 4;
            const int b1r = b0 + 16 * 256;
            const v8s a0 = *(const v8s*)(Tl[buf] + b0);
            const v8s a1 = *(const v8s*)(Tl[buf] + b1r);
#pragma unroll
            for (int nt = 0; nt < 4; ++nt) {
                acc0[nt] = __builtin_amdgcn_mfma_f32_16x16x32_bf16(a0, Bf[nt][kt], acc0[nt], 0, 0, 0);
                acc1[nt] = __builtin_amdgcn_mfma_f32_16x16x32_bf16(a1, Bf[nt][kt], acc1[nt], 0, 0, 0);
            }
        }
        // ---- epilogue ----
        float part[8];
#pragma unroll
        for (int c = 0; c < 8; ++c) part[c] = 0.f;
#pragma unroll
        for (int nt = 0; nt < 4; ++nt) {
            float mv = fmaxf(fmaxf(acc0[nt][0], acc0[nt][1]),
                             fmaxf(acc0[nt][2], acc0[nt][3]));
            mv = fmaxf(mv, __shfl_xor(mv, 16));
            mv = fmaxf(mv, __shfl_xor(mv, 32));
            const float s16 = __shfl(acc1[nt][0], lmod);
            const float h = fmaxf(fmaxf(mv, s16) + b4c[nt], 0.f);
#pragma unroll
            for (int c = 0; c < 8; ++c) part[c] = fmaf(h, wcls[nt][c], part[c]);
        }
#pragma unroll
        for (int c = 0; c < 8; ++c) {
            part[c] += __shfl_xor(part[c], 1);
            part[c] += __shfl_xor(part[c], 2);
            part[c] += __shfl_xor(part[c], 4);
            part[c] += __shfl_xor(part[c], 8);
        }
        if (lane == 0) {
#pragma unroll
            for (int c = 0; c < 8; ++c) sh_part[buf][wv][c] = part[c];
        }
        // ---- build T for p+1 into buf^1 ----
        if (p < PTS4 - 1) {
#pragma unroll
            for (int it = 0; it < 5; ++it) {
                const int m = it * 4 + wv;
                if (m <= 16) {
                    const float rx = qNx[it] - cNx, ry = qNy[it] - cNy, rz = qNz[it] - cNz;
                    float pa = aNx[it];
                    pa = fmaf(rx, bw0a, pa); pa = fmaf(ry, bw1a, pa); pa = fmaf(rz, bw2a, pa);
                    float pb = aNy[it];
                    pb = fmaf(rx, bw0b, pb); pb = fmaf(ry, bw1b, pb); pb = fmaf(rz, bw2b, pb);
                    const float ta = fmaf(fmaxf(pa, 0.f), sa, oa);
                    const float tb = fmaf(fmaxf(pb, 0.f), sb, ob);
                    const unsigned int w = (unsigned int)f2bf(ta) | ((unsigned int)f2bf(tb) << 16);
                    int byte = m * 256 + ch0 * 2;
                    byte ^= (m & 7) << 4;
                    *(unsigned int*)(Tl[buf ^ 1] + byte) = w;
                }
            }
        }
        __syncthreads();
        // ---- output for p (reads sh_part[buf]; next write targets buf^1) ----
        if (tid < 8) {
            const float z = sh_part[buf][0][tid] + sh_part[buf][1][tid] +
                            sh_part[buf][2][tid] + sh_part[buf][3][tid] + bc[tid];
            float mz = z;
            mz = fmaxf(mz, __shfl_xor(mz, 1));
            mz = fmaxf(mz, __shfl_xor(mz, 2));
            mz = fmaxf(mz, __shfl_xor(mz, 4));
            const float e = expf(z - mz);
            float se = e;
            se += __shfl_xor(se, 1);
            se += __shfl_xor(se, 2);
            se += __shfl_xor(se, 4);
            out[(size_t)(base + p) * 8 + tid] = z - mz - logf(se);
        }
    }
}

extern "C" void kernel_launch(void* const* d_in, const int* in_sizes, int n_in,
                              void* d_out, int out_size, void* d_ws, size_t ws_size,
                              hipStream_t stream) {
    const float* pos = (const float*)d_in[0];
    const int*   nbr = (const int*)d_in[1];
    const float* W1  = (const float*)d_in[2];
    const float* b1  = (const float*)d_in[3];
    const float* g1  = (const float*)d_in[4];
    const float* bt1 = (const float*)d_in[5];
    const float* m1  = (const float*)d_in[6];
    const float* v1  = (const float*)d_in[7];
    const float* W2  = (const float*)d_in[8];
    const float* b2  = (const float*)d_in[9];
    const float* W3  = (const float*)d_in[10];
    const float* b3  = (const float*)d_in[11];
    const float* g2  = (const float*)d_in[12];
    const float* bt2 = (const float*)d_in[13];
    const float* m2  = (const float*)d_in[14];
    const float* v2  = (const float*)d_in[15];
    const float* W4  = (const float*)d_in[16];
    const float* b4  = (const float*)d_in[17];
    const float* Wc  = (const float*)d_in[18];
    const float* bc  = (const float*)d_in[19];
    float* out = (float*)d_out;

    float* B1 = (float*)d_ws;                 // 40000*64  = 10.24 MB
    float* A2 = B1 + (size_t)NPTS * 64;       // 40000*128 = 20.48 MB

    k1_b1<<<NPTS / 4, 256, 0, stream>>>(pos, nbr, W1, b1, B1);
    k2_conv1_mfma<<<NPTS / PTS2, 256, 0, stream>>>(pos, nbr, B1, W1, g1, bt1, m1, v1,
                                                   W2, b2, W3, b3, A2);
    k4_conv2_mfma<<<NPTS / PTS4, 256, 0, stream>>>(pos, nbr, A2, W3, g2, bt2, m2, v2,
                                                   W4, b4, Wc, bc, out);
}